// Round 1
// 354.078 us; speedup vs baseline: 1.2159x; 1.2159x over previous
//
#include <hip/hip_runtime.h>
#include <stdint.h>
#include <math.h>

// B=4, T=2048, D=1024, H=16, DK=64.
// Inputs fp32, output fp32; internal compute bf16 MFMA + fp32 accum.
typedef __attribute__((ext_vector_type(8))) __bf16 bf16x8;
typedef __attribute__((ext_vector_type(4))) float f32x4;

__device__ __forceinline__ void load_lds16(const void* g, void* l) {
  __builtin_amdgcn_global_load_lds((__attribute__((address_space(1))) void*)(g),
                                   (__attribute__((address_space(3))) void*)(l),
                                   16, 0, 0);
}

// ---------------- x (fp32) -> bf16 canonical copy ----------------
__global__ __launch_bounds__(256)
void convert_x(const float* __restrict__ xf, __bf16* __restrict__ xb) {
  const size_t i = ((size_t)blockIdx.x * 256 + threadIdx.x) * 8;  // n = 8388608 exact
  const float4 u0 = *(const float4*)(xf + i);
  const float4 u1 = *(const float4*)(xf + i + 4);
  bf16x8 v;
  v[0] = (__bf16)u0.x; v[1] = (__bf16)u0.y; v[2] = (__bf16)u0.z; v[3] = (__bf16)u0.w;
  v[4] = (__bf16)u1.x; v[5] = (__bf16)u1.y; v[6] = (__bf16)u1.z; v[7] = (__bf16)u1.w;
  *(bf16x8*)&xb[i] = v;
}

// ---------------- weight transpose ([K,N] fp32 -> [N,K] bf16) + bias pack ----------------
__global__ __launch_bounds__(256)
void prep_weights(const float* __restrict__ Wq, const float* __restrict__ Wk,
                  const float* __restrict__ Wv, const float* __restrict__ Wo,
                  const float* __restrict__ bq, const float* __restrict__ bk,
                  const float* __restrict__ bv, const float* __restrict__ bo,
                  __bf16* __restrict__ Bt1, __bf16* __restrict__ Bt2,
                  float* __restrict__ bqkv, float* __restrict__ bo_f) {
  const int m = blockIdx.z;  // 0=Wq 1=Wk 2=Wv 3=Wo
  const float* W = (m == 0) ? Wq : (m == 1) ? Wk : (m == 2) ? Wv : Wo;
  __bf16* Out = (m == 3) ? Bt2 : Bt1 + (size_t)m * 1024 * 1024;
  const int kt = blockIdx.x * 64, nt = blockIdx.y * 64;
  __shared__ __bf16 tile[64 * 68];
  const int t = threadIdx.x;
#pragma unroll
  for (int i = 0; i < 16; i++) {
    int e = i * 256 + t;
    int r = e >> 6, c = e & 63;
    tile[r * 68 + c] = (__bf16)W[(size_t)(kt + r) * 1024 + nt + c];
  }
  __syncthreads();
#pragma unroll
  for (int i = 0; i < 16; i++) {
    int e = i * 256 + t;
    int r = e >> 6, c = e & 63;
    Out[(size_t)(nt + r) * 1024 + kt + c] = tile[c * 68 + r];
  }
  if (blockIdx.x == 0 && blockIdx.y == 0) {
    if (m < 3) {
      const float* bsrc = (m == 0) ? bq : (m == 1) ? bk : bv;
      for (int i = t; i < 1024; i += 256) bqkv[m * 1024 + i] = bsrc[i];
    } else {
      for (int i = t; i < 1024; i += 256) bo_f[i] = bo[i];
    }
  }
}

// ---------------- GEMM: C[M,N] = A[M,K] @ Bt[N,K]^T + bias[N] ----------------
// m97 recipe: 128x128 tile, 256 thr (4 waves 2x2), BK=32, global_load_lds w=16.
__global__ __launch_bounds__(256)
void gemm_bt(const __bf16* __restrict__ A, const __bf16* __restrict__ Bt,
             const float* __restrict__ bias, void* __restrict__ Cv,
             int out_f32, int M, int N, int K) {
  __shared__ __align__(16) __bf16 As[128 * 32];
  __shared__ __align__(16) __bf16 Bs[128 * 32];
  const int t = threadIdx.x;
  const int lane = t & 63;
  const int wave = t >> 6;
  const int bm = blockIdx.x * 128;
  const int bn = blockIdx.y * 128;
  const int wm = (wave >> 1) * 64;
  const int wn = (wave & 1) * 64;
  const int fm = lane & 15, fk = (lane >> 4) * 8;
  f32x4 acc[4][4] = {};

  const int r0 = t >> 2, kc = (t & 3) * 8;
  const __bf16* Ag0 = A + (size_t)(bm + r0) * K + kc;
  const __bf16* Ag1 = A + (size_t)(bm + 64 + r0) * K + kc;
  const __bf16* Bg0 = Bt + (size_t)(bn + r0) * K + kc;
  const __bf16* Bg1 = Bt + (size_t)(bn + 64 + r0) * K + kc;

  for (int k0 = 0; k0 < K; k0 += 32) {
    load_lds16(Ag0 + k0, &As[t * 8]);
    load_lds16(Ag1 + k0, &As[2048 + t * 8]);
    load_lds16(Bg0 + k0, &Bs[t * 8]);
    load_lds16(Bg1 + k0, &Bs[2048 + t * 8]);
    asm volatile("s_waitcnt vmcnt(0)" ::: "memory");
    __syncthreads();
    bf16x8 af[4], bfr[4];
#pragma unroll
    for (int i = 0; i < 4; i++) {
      af[i] = *(const bf16x8*)&As[(wm + i * 16 + fm) * 32 + fk];
      bfr[i] = *(const bf16x8*)&Bs[(wn + i * 16 + fm) * 32 + fk];
    }
#pragma unroll
    for (int i = 0; i < 4; i++)
#pragma unroll
      for (int j = 0; j < 4; j++)
        acc[i][j] = __builtin_amdgcn_mfma_f32_16x16x32_bf16(af[i], bfr[j], acc[i][j], 0, 0, 0);
    __syncthreads();
  }

  const int cm = (lane >> 4) * 4, cn = lane & 15;
#pragma unroll
  for (int i = 0; i < 4; i++)
#pragma unroll
    for (int j = 0; j < 4; j++) {
      const int col = bn + wn + j * 16 + cn;
      const float bvv = bias[col];
#pragma unroll
      for (int r = 0; r < 4; r++) {
        const int row = bm + wm + i * 16 + cm + r;
        const float val = acc[i][j][r] + bvv;
        if (out_f32) ((float*)Cv)[(size_t)row * N + col] = val;
        else ((__bf16*)Cv)[(size_t)row * N + col] = (__bf16)val;
      }
    }
}

// ---------------- V transpose: QKV cols[2048:3072) -> Vt[B,H,DK,T] ----------------
__global__ __launch_bounds__(256)
void transpose_v(const __bf16* __restrict__ QKV, __bf16* __restrict__ Vt) {
  const int tt = blockIdx.x;
  const int bh = blockIdx.y;
  const int b = bh >> 4, h = bh & 15;
  __shared__ __bf16 tile[64 * 68];
  const int t = threadIdx.x;
#pragma unroll
  for (int i = 0; i < 16; i++) {
    int e = i * 256 + t;
    int tok = e >> 6, dk = e & 63;
    tile[tok * 68 + dk] =
        QKV[((size_t)b * 2048 + tt * 64 + tok) * 3072 + 2048 + h * 64 + dk];
  }
  __syncthreads();
#pragma unroll
  for (int i = 0; i < 16; i++) {
    int e = i * 256 + t;
    int dk = e >> 6, tok = e & 63;
    Vt[((size_t)bh * 64 + dk) * 2048 + tt * 64 + tok] = tile[tok * 68 + dk];
  }
}

// ---------------- flash attention, causal, DK=64 ----------------
// grid (64 bh, 16 qt-slots): 128 q-rows/block, 4 waves, wave owns 32 rows.
// qt-slot map partitions {0..15} into residue-4 classes, each class summing to
// 68 k-iterations: under linear round-robin block->CU placement every CU slot
// carries equal work (old x-fastest layout gave a 16:1 CU imbalance).
// Per iter: 2 barriers (P-buffer is per-wave, needs no barrier), next K/V tile
// prefetched into registers after the staging barrier (latency hides under
// QK^T+softmax+PV), softmax in exp2 domain with folded 0.125*log2(e) scale.
__global__ __launch_bounds__(256)
void flash_attn(const __bf16* __restrict__ QKV, const __bf16* __restrict__ Vt,
                __bf16* __restrict__ O) {
  const int y = blockIdx.y;
  const int g = y >> 2, iy = y & 3;
  // classes (y&3): {15,0,14,1} {13,2,12,3} {11,4,10,5} {9,6,8,7} — each sums
  // to 68 iters, heavy block first within each class.
  const int qt = (g == 0) ? (15 - 2 * iy)
               : (g == 1) ? (2 * iy)
               : (g == 2) ? (14 - 2 * iy)
                          : (2 * iy + 1);
  const int bh = blockIdx.x;
  const int b = bh >> 4, h = bh & 15;
  __shared__ __align__(16) __bf16 Ks[64 * 72];      // [ktok][dk] pad 72
  __shared__ __align__(16) __bf16 Vs[64 * 72];      // [dk][ktok] pad 72
  __shared__ __align__(16) __bf16 Ps[4 * 32 * 72];  // per-wave [32 qrow][64 tok] pad 72
  const int t = threadIdx.x, lane = t & 63, wave = t >> 6;
  const int fm = lane & 15, fq = lane >> 4;

  // Q fragments from global (dk-contiguous = A-frag layout)
  bf16x8 qf[2][2];
#pragma unroll
  for (int mi = 0; mi < 2; mi++) {
    const size_t qrow =
        ((size_t)b * 2048 + qt * 128 + wave * 32 + mi * 16 + fm) * 3072 + h * 64;
    qf[mi][0] = *(const bf16x8*)&QKV[qrow + fq * 8];
    qf[mi][1] = *(const bf16x8*)&QKV[qrow + 32 + fq * 8];
  }

  f32x4 o_acc[2][4] = {};
  float m_i[2][4], l_i[2][4];
#pragma unroll
  for (int mi = 0; mi < 2; mi++)
#pragma unroll
    for (int r = 0; r < 4; r++) { m_i[mi][r] = -1e30f; l_i[mi][r] = 0.f; }

  const int tok0 = t >> 3, ck = (t & 7) * 8;
  const size_t kbase = ((size_t)b * 2048) * 3072 + 1024 + h * 64;
  const size_t vbase = (size_t)bh * 64 * 2048;
  __bf16* Pw = &Ps[wave * 32 * 72];
  const int nkt = 2 * qt + 2;
  const int qmax_w = qt * 128 + wave * 32 + 31;  // last unmasked k for this wave
  const float SC = 0.18033688011112042f;         // log2(e) / sqrt(64)

  // prologue: prefetch tile kt=0 into registers
  bf16x8 pk0 = *(const bf16x8*)&QKV[kbase + (size_t)tok0 * 3072 + ck];
  bf16x8 pk1 = *(const bf16x8*)&QKV[kbase + (size_t)(32 + tok0) * 3072 + ck];
  bf16x8 pv0 = *(const bf16x8*)&Vt[vbase + (size_t)tok0 * 2048 + ck];
  bf16x8 pv1 = *(const bf16x8*)&Vt[vbase + (size_t)(32 + tok0) * 2048 + ck];

  for (int kt = 0; kt < nkt; kt++) {
    const int kb = kt * 64;
    __syncthreads();  // prior iteration's LDS reads complete
    *(bf16x8*)&Ks[tok0 * 72 + ck] = pk0;
    *(bf16x8*)&Ks[(tok0 + 32) * 72 + ck] = pk1;
    *(bf16x8*)&Vs[tok0 * 72 + ck] = pv0;
    *(bf16x8*)&Vs[(tok0 + 32) * 72 + ck] = pv1;
    __syncthreads();  // staging visible

    // prefetch next tile AFTER the barrier (barrier drains vmcnt; issuing here
    // lets the loads fly across the whole compute phase)
    if (kt + 1 < nkt) {
      const int kn = kb + 64;
      pk0 = *(const bf16x8*)&QKV[kbase + (size_t)(kn + tok0) * 3072 + ck];
      pk1 = *(const bf16x8*)&QKV[kbase + (size_t)(kn + 32 + tok0) * 3072 + ck];
      pv0 = *(const bf16x8*)&Vt[vbase + (size_t)tok0 * 2048 + kn + ck];
      pv1 = *(const bf16x8*)&Vt[vbase + (size_t)(32 + tok0) * 2048 + kn + ck];
    }

    // fully causal-masked for this wave's 32 q-rows? (only possible on the
    // final diagonal tile: waves 0,1 skip it). Barriers already done.
    if (kb > qmax_w) continue;

    // S = Q K^T  (2 m-tiles x 4 n-tiles)
    f32x4 s[2][4];
#pragma unroll
    for (int nt = 0; nt < 4; nt++) {
      const bf16x8 kf0 = *(const bf16x8*)&Ks[(nt * 16 + fm) * 72 + fq * 8];
      const bf16x8 kf1 = *(const bf16x8*)&Ks[(nt * 16 + fm) * 72 + 32 + fq * 8];
#pragma unroll
      for (int mi = 0; mi < 2; mi++) {
        f32x4 z = {};
        z = __builtin_amdgcn_mfma_f32_16x16x32_bf16(qf[mi][0], kf0, z, 0, 0, 0);
        z = __builtin_amdgcn_mfma_f32_16x16x32_bf16(qf[mi][1], kf1, z, 0, 0, 0);
        s[mi][nt] = z;
      }
    }
    // scale into exp2 domain (+ causal mask only on the two diagonal k-tiles)
    if (kt >= 2 * qt) {
#pragma unroll
      for (int mi = 0; mi < 2; mi++) {
        const int qg = qt * 128 + wave * 32 + mi * 16 + fq * 4;
#pragma unroll
        for (int nt = 0; nt < 4; nt++)
#pragma unroll
          for (int r = 0; r < 4; r++) {
            float v = s[mi][nt][r] * SC;
            if ((kb + nt * 16 + fm) > (qg + r)) v = -1e30f;
            s[mi][nt][r] = v;
          }
      }
    } else {
#pragma unroll
      for (int mi = 0; mi < 2; mi++)
#pragma unroll
        for (int nt = 0; nt < 4; nt++)
#pragma unroll
          for (int r = 0; r < 4; r++) s[mi][nt][r] *= SC;
    }

    // online softmax in exp2 domain (rows across 16 fm-lanes per fq group)
    float rmax[2][4], rsum[2][4], alpha[2][4];
#pragma unroll
    for (int mi = 0; mi < 2; mi++)
#pragma unroll
      for (int r = 0; r < 4; r++)
        rmax[mi][r] = fmaxf(fmaxf(s[mi][0][r], s[mi][1][r]),
                            fmaxf(s[mi][2][r], s[mi][3][r]));
#pragma unroll
    for (int off = 1; off < 16; off <<= 1)
#pragma unroll
      for (int mi = 0; mi < 2; mi++)
#pragma unroll
        for (int r = 0; r < 4; r++)
          rmax[mi][r] = fmaxf(rmax[mi][r], __shfl_xor(rmax[mi][r], off, 64));
#pragma unroll
    for (int mi = 0; mi < 2; mi++)
#pragma unroll
      for (int r = 0; r < 4; r++) {
        const float mn = fmaxf(m_i[mi][r], rmax[mi][r]);
        alpha[mi][r] = exp2f(m_i[mi][r] - mn);
        m_i[mi][r] = mn;
        rsum[mi][r] = 0.f;
      }
#pragma unroll
    for (int mi = 0; mi < 2; mi++)
#pragma unroll
      for (int nt = 0; nt < 4; nt++)
#pragma unroll
        for (int r = 0; r < 4; r++) {
          const float p = exp2f(s[mi][nt][r] - m_i[mi][r]);
          s[mi][nt][r] = p;
          rsum[mi][r] += p;
        }
#pragma unroll
    for (int off = 1; off < 16; off <<= 1)
#pragma unroll
      for (int mi = 0; mi < 2; mi++)
#pragma unroll
        for (int r = 0; r < 4; r++)
          rsum[mi][r] += __shfl_xor(rsum[mi][r], off, 64);
#pragma unroll
    for (int mi = 0; mi < 2; mi++)
#pragma unroll
      for (int r = 0; r < 4; r++)
        l_i[mi][r] = l_i[mi][r] * alpha[mi][r] + rsum[mi][r];

    // P: C-layout -> per-wave LDS -> A-layout (no barrier needed: wave-local,
    // compiler inserts the lgkmcnt ordering)
#pragma unroll
    for (int mi = 0; mi < 2; mi++)
#pragma unroll
      for (int nt = 0; nt < 4; nt++)
#pragma unroll
        for (int r = 0; r < 4; r++)
          Pw[(mi * 16 + fq * 4 + r) * 72 + nt * 16 + fm] = (__bf16)s[mi][nt][r];

    bf16x8 pf[2][2];
#pragma unroll
    for (int mi = 0; mi < 2; mi++) {
      pf[mi][0] = *(const bf16x8*)&Pw[(mi * 16 + fm) * 72 + fq * 8];
      pf[mi][1] = *(const bf16x8*)&Pw[(mi * 16 + fm) * 72 + 32 + fq * 8];
    }
#pragma unroll
    for (int dt = 0; dt < 4; dt++) {
      const bf16x8 vf0 = *(const bf16x8*)&Vs[(dt * 16 + fm) * 72 + fq * 8];
      const bf16x8 vf1 = *(const bf16x8*)&Vs[(dt * 16 + fm) * 72 + 32 + fq * 8];
#pragma unroll
      for (int mi = 0; mi < 2; mi++) {
        f32x4 o = o_acc[mi][dt];
#pragma unroll
        for (int r = 0; r < 4; r++) o[r] *= alpha[mi][r];
        o = __builtin_amdgcn_mfma_f32_16x16x32_bf16(pf[mi][0], vf0, o, 0, 0, 0);
        o = __builtin_amdgcn_mfma_f32_16x16x32_bf16(pf[mi][1], vf1, o, 0, 0, 0);
        o_acc[mi][dt] = o;
      }
    }
  }

#pragma unroll
  for (int mi = 0; mi < 2; mi++)
#pragma unroll
    for (int r = 0; r < 4; r++) l_i[mi][r] = 1.f / l_i[mi][r];
#pragma unroll
  for (int mi = 0; mi < 2; mi++) {
    const size_t orow = (size_t)b * 2048 + qt * 128 + wave * 32 + mi * 16 + fq * 4;
#pragma unroll
    for (int dt = 0; dt < 4; dt++)
#pragma unroll
      for (int r = 0; r < 4; r++)
        O[(orow + r) * 1024 + h * 64 + dt * 16 + fm] =
            (__bf16)(o_acc[mi][dt][r] * l_i[mi][r]);
  }
}

// ---------------- launch ----------------
extern "C" void kernel_launch(void* const* d_in, const int* in_sizes, int n_in,
                              void* d_out, int out_size, void* d_ws, size_t ws_size,
                              hipStream_t stream) {
  const float* x = (const float*)d_in[0];
  const float* Wq = (const float*)d_in[1];
  const float* bq = (const float*)d_in[2];
  const float* Wk = (const float*)d_in[3];
  const float* bk = (const float*)d_in[4];
  const float* Wv = (const float*)d_in[5];
  const float* bv = (const float*)d_in[6];
  const float* Wo = (const float*)d_in[7];
  const float* bo = (const float*)d_in[8];

  // workspace layout (bytes), ~92 MB total
  char* ws = (char*)d_ws;
  __bf16* Bt1 = (__bf16*)(ws);               // [3072,1024] WqT|WkT|WvT  (6 MB)
  __bf16* Bt2 = (__bf16*)(ws + 6291456);     // [1024,1024] WoT          (2 MB)
  float* bqkv = (float*)(ws + 8388608);      // [3072] f32
  float* bo_f = (float*)(ws + 8400896);      // [1024] f32
  __bf16* QKV = (__bf16*)(ws + 8405504);     // [8192,3072]              (48 MB)
  __bf16* Vt = (__bf16*)(ws + 58737152);     // [4,16,64,2048]           (16 MB)
  __bf16* Xb = (__bf16*)(ws + 75514368);     // [8192,1024] bf16 x       (16 MB)
  __bf16* Ow = Xb;  // Xb dead after gemm1; flash output reuses the region

  hipLaunchKernelGGL(convert_x, dim3(4096), dim3(256), 0, stream, x, Xb);
  hipLaunchKernelGGL(prep_weights, dim3(16, 16, 4), dim3(256), 0, stream,
                     Wq, Wk, Wv, Wo, bq, bk, bv, bo, Bt1, Bt2, bqkv, bo_f);
  hipLaunchKernelGGL(gemm_bt, dim3(64, 24), dim3(256), 0, stream,
                     Xb, Bt1, bqkv, (void*)QKV, 0, 8192, 3072, 1024);
  hipLaunchKernelGGL(transpose_v, dim3(32, 64), dim3(256), 0, stream, QKV, Vt);
  hipLaunchKernelGGL(flash_attn, dim3(64, 16), dim3(256), 0, stream, QKV, Vt, Ow);
  hipLaunchKernelGGL(gemm_bt, dim3(64, 8), dim3(256), 0, stream,
                     Ow, Bt2, bo_f, d_out, 1, 8192, 1024, 1024);
}